// Round 12
// baseline (43.538 us; speedup 1.0000x reference)
//
#include <hip/hip_runtime.h>

#define K_SEGS 8192
#define ALPHA_W 0.5f
#define NEG_INF_BITS 0xFF800000
#define WIN 64            // id window per block (chunk spans ~5 ids; 64 = 12x margin)
#define NBLOCKS 2048
#define BLOCK 256
#define SHARD_SZ 32                       // blocks per ticket shard
#define NSHARDS (NBLOCKS / SHARD_SZ)      // 64 shards

// ws layout (unsigned words):
//   [0      .. 8191 ]   seg_sum  (float)
//   [8192   .. 16383]   seg_maxb (unsigned float-bits; init 0 valid since loss >= 0)
//   [16384  .. 24575]   seg_cnt  (unsigned; #blocks touching -> presence)
//   [24576  ..]         shard tickets (one per 64B line), then stage2 ticket
#define SHARD_BASE (3 * K_SEGS)
#define STAGE2_OFF (SHARD_BASE + NSHARDS * 16)
#define WS_WORDS (STAGE2_OFF + 16)

// ---------------------------------------------------------------------------
// Kernel 0: zero accumulators + tickets (ws poisoned 0xAA, never re-poisoned)
// ---------------------------------------------------------------------------
__global__ void init_ws_kernel(unsigned* __restrict__ w) {
    int i = blockIdx.x * blockDim.x + threadIdx.x;
    if (i < WS_WORDS) w[i] = 0u;
}

// ---------------------------------------------------------------------------
// Kernel 1 (fused): UNIT-STRIDE loads, pair-softmax (lane l + lane l^1 share
// one node), LDS-privatized segmented sum/max, sharded ticket, pipelined
// finalize. R11 lesson: stride-32 lane addressing delivered every L2 line
// twice; half-node-per-lane makes every dwordx4 unit-stride.
// ---------------------------------------------------------------------------
__global__ __launch_bounds__(BLOCK) void node_loss_kernel(
        const float* __restrict__ logits,   // [N, 8]
        const int* __restrict__ targets,    // [N]
        const int* __restrict__ cid,        // [N], sorted
        float* __restrict__ seg_sum,        // [K]
        unsigned* __restrict__ seg_maxb,    // [K]
        unsigned* __restrict__ seg_cnt,     // [K]
        unsigned* __restrict__ shard_tk,    // [NSHARDS*16]
        unsigned* __restrict__ stage2_tk,   // [16]
        float* __restrict__ out,
        int n) {
    __shared__ float lsum[WIN];
    __shared__ int   lmax[WIN];
    __shared__ unsigned s_last;
    __shared__ float s_fa[4], s_fn[4];

    const int tid  = threadIdx.x;
    const int lane = tid & 63;
    const int wv   = tid >> 6;            // wave id 0..3

    const int chunk  = (n + NBLOCKS - 1) / NBLOCKS;   // 1954 for N=4M
    const int cstart = blockIdx.x * chunk;

    if (cstart < n) {
        const int cend = min(cstart + chunk, n);
        const int base = cid[cstart];                 // broadcast load

        for (int j = tid; j < WIN; j += BLOCK) {
            lsum[j] = 0.0f;
            lmax[j] = (int)NEG_INF_BITS;
        }
        __syncthreads();

        const float4* lgf = reinterpret_cast<const float4*>(logits);

        // wave-uniform loop: wave wv handles nodes [wstart, wstart+128) per iter
        for (int wstart = cstart + wv * 128; wstart < cend; wstart += BLOCK * 2) {
            const int wlast = min(wstart + 127, cend - 1);
            const int ufirst = cid[wstart];           // broadcast (sorted)
            const int ulast  = cid[wlast];            // broadcast
            const int ubase  = ufirst - base;
            const bool uniform = (ufirst == ulast) && (ubase < WIN);

            float loss[4];
            // 4 unit-stride float4 loads: lane l, load j -> half-node h=j*64+l
            #pragma unroll
            for (int j = 0; j < 4; ++j) {
                const int h = j * 64 + lane;          // [0,256)
                const int node = wstart + (h >> 1);
                const bool v = (node < cend);
                float4 x;
                if (v) x = lgf[(size_t)wstart * 2 + h];
                else   x = make_float4(0.f, 0.f, 0.f, 0.f);

                // pair softmax across lane^1 (partner holds other 4 classes)
                float m4 = fmaxf(fmaxf(x.x, x.y), fmaxf(x.z, x.w));
                float m8 = fmaxf(m4, __shfl_xor(m4, 1));
                float s4 = __expf(x.x - m8) + __expf(x.y - m8)
                         + __expf(x.z - m8) + __expf(x.w - m8);
                float s8 = s4 + __shfl_xor(s4, 1);
                float lse = __logf(s8) + m8;

                int t = v ? targets[node] : 0;
                // own half holds classes [4*(lane&1) .. +3]
                float xsel = (t & 2) ? ((t & 1) ? x.w : x.z)
                                     : ((t & 1) ? x.y : x.x);
                float xc = ((t >> 2) == (lane & 1)) ? xsel : -1e30f;
                float xt = fmaxf(xc, __shfl_xor(xc, 1));

                float ce = lse - xt;          // >= 0
                float pt = __expf(-ce);       // (0,1]
                float om = 1.0f - pt;
                loss[j] = v ? om * om * ce : 0.0f;   // both pair lanes identical
            }

            if (uniform) {
                // all nodes this iter in one segment: butterfly; pair-duplicate -> 0.5x
                float tsum = (loss[0] + loss[1]) + (loss[2] + loss[3]);
                float tmax = fmaxf(fmaxf(loss[0], loss[1]), fmaxf(loss[2], loss[3]));
                #pragma unroll
                for (int o = 32; o > 0; o >>= 1) {
                    tsum += __shfl_xor(tsum, o);
                    tmax = fmaxf(tmax, __shfl_xor(tmax, o));
                }
                if (lane == 0) {
                    atomicAdd(&lsum[ubase], 0.5f * tsum);
                    atomicMax(&lmax[ubase], __float_as_int(tmax));
                }
            } else {
                // boundary wave-iter (~26%): even pair-lane writes its 4 nodes
                if ((lane & 1) == 0) {
                    #pragma unroll
                    for (int j = 0; j < 4; ++j) {
                        const int node = wstart + j * 32 + (lane >> 1);
                        if (node < cend) {
                            const int cn = cid[node];
                            const int off = cn - base;
                            if (off < WIN) {
                                atomicAdd(&lsum[off], loss[j]);
                                atomicMax(&lmax[off], __float_as_int(loss[j]));
                            } else {  // pathological overflow: global accumulate
                                atomicAdd(&seg_sum[cn], loss[j]);
                                atomicMax(&seg_maxb[cn], __float_as_uint(loss[j]));
                                atomicAdd(&seg_cnt[cn], 1u);
                            }
                        }
                    }
                }
            }
        }
        __syncthreads();

        // flush touched window entries: ~5-10 global atomic triples per block
        for (int j = tid; j < WIN; j += BLOCK) {
            int mb = lmax[j];
            if (mb != (int)NEG_INF_BITS) {
                atomicAdd(&seg_sum[base + j], lsum[j]);
                atomicMax(&seg_maxb[base + j], (unsigned)mb);  // mb >= 0 bits
                atomicAdd(&seg_cnt[base + j], 1u);
            }
        }
    }

    // ---- sharded ticket: last finished block overall runs the finalize ----
    asm volatile("s_waitcnt vmcnt(0)" ::: "memory");  // own flush atomics acked
    __syncthreads();                                  // whole block drained
    if (tid == 0) {
        unsigned fin = 0u;
        unsigned my = atomicAdd(&shard_tk[(blockIdx.x / SHARD_SZ) * 16], 1u);
        if (my == (unsigned)(SHARD_SZ - 1)) {
            fin = atomicAdd(&stage2_tk[0], 1u) + 1u;
        }
        s_last = (fin == (unsigned)NSHARDS) ? 1u : 0u;
    }
    __syncthreads();
    if (s_last) {
        float acc = 0.0f, np = 0.0f;
        // Pipelined: unconditional agent-scope loads, unrolled -> many in flight
        #pragma unroll 8
        for (int k = tid; k < K_SEGS; k += BLOCK) {
            unsigned c = __hip_atomic_load(&seg_cnt[k],  __ATOMIC_RELAXED, __HIP_MEMORY_SCOPE_AGENT);
            float s    = __hip_atomic_load(&seg_sum[k],  __ATOMIC_RELAXED, __HIP_MEMORY_SCOPE_AGENT);
            unsigned m = __hip_atomic_load(&seg_maxb[k], __ATOMIC_RELAXED, __HIP_MEMORY_SCOPE_AGENT);
            if (c != 0u) {
                acc += ALPHA_W * s + (1.0f - ALPHA_W) * __uint_as_float(m);
                np += 1.0f;
            }
        }
        #pragma unroll
        for (int o = 32; o > 0; o >>= 1) {
            acc += __shfl_xor(acc, o);
            np  += __shfl_xor(np, o);
        }
        if (lane == 0) { s_fa[tid >> 6] = acc; s_fn[tid >> 6] = np; }
        __syncthreads();
        if (tid == 0) {
            float a = s_fa[0] + s_fa[1] + s_fa[2] + s_fa[3];
            float c = s_fn[0] + s_fn[1] + s_fn[2] + s_fn[3];
            out[0] = a / fmaxf(c, 1.0f);
        }
    }
}

// ---------------------------------------------------------------------------
extern "C" void kernel_launch(void* const* d_in, const int* in_sizes, int n_in,
                              void* d_out, int out_size, void* d_ws, size_t ws_size,
                              hipStream_t stream) {
    const float* logits = (const float*)d_in[0];
    const int* targets  = (const int*)d_in[1];
    const int* cid      = (const int*)d_in[2];
    float* out          = (float*)d_out;

    const int n = in_sizes[1];   // N = 4,000,000

    unsigned* w        = (unsigned*)d_ws;
    float* seg_sum     = (float*)w;
    unsigned* seg_maxb = w + K_SEGS;
    unsigned* seg_cnt  = w + 2 * K_SEGS;
    unsigned* shard_tk = w + SHARD_BASE;
    unsigned* stage2_tk= w + STAGE2_OFF;

    init_ws_kernel<<<(WS_WORDS + 255) / 256, 256, 0, stream>>>(w);

    node_loss_kernel<<<NBLOCKS, BLOCK, 0, stream>>>(logits, targets, cid,
                                                    seg_sum, seg_maxb, seg_cnt,
                                                    shard_tk, stage2_tk, out, n);
}

// Round 13
// 42.183 us; speedup vs baseline: 1.0321x; 1.0321x over previous
//
#include <hip/hip_runtime.h>

#define K_SEGS 8192
#define ALPHA_W 0.5f
#define NEG_INF_BITS 0xFF800000
#define WIN 64            // id window per block (chunk spans ~5 ids; 64 = 12x margin)
#define NBLOCKS 2048
#define BLOCK 256
#define SHARD_SZ 32                       // blocks per ticket shard
#define NSHARDS (NBLOCKS / SHARD_SZ)      // 64 shards

// ws layout (unsigned words):
//   [0      .. 8191 ]   seg_sum  (float)
//   [8192   .. 16383]   seg_maxb (unsigned float-bits; init 0 valid since loss >= 0)
//   [16384  .. 24575]   seg_cnt  (unsigned; #blocks touching -> presence)
//   [24576  ..]         shard tickets (one per 64B line), then stage2 ticket
#define SHARD_BASE (3 * K_SEGS)
#define STAGE2_OFF (SHARD_BASE + NSHARDS * 16)
#define WS_WORDS (STAGE2_OFF + 16)

// ---------------------------------------------------------------------------
// Kernel 0: zero accumulators + tickets (ws poisoned 0xAA, never re-poisoned)
// ---------------------------------------------------------------------------
__global__ void init_ws_kernel(unsigned* __restrict__ w) {
    int i = blockIdx.x * blockDim.x + threadIdx.x;
    if (i < WS_WORDS) w[i] = 0u;
}

// ---------------------------------------------------------------------------
// focal loss for one node given its 8 logits + target
// ---------------------------------------------------------------------------
__device__ __forceinline__ float node_focal(float4 a, float4 b, int t) {
    float x0 = a.x, x1 = a.y, x2 = a.z, x3 = a.w;
    float x4 = b.x, x5 = b.y, x6 = b.z, x7 = b.w;
    float m = fmaxf(fmaxf(fmaxf(x0, x1), fmaxf(x2, x3)),
                    fmaxf(fmaxf(x4, x5), fmaxf(x6, x7)));
    float s = __expf(x0 - m) + __expf(x1 - m) + __expf(x2 - m) + __expf(x3 - m)
            + __expf(x4 - m) + __expf(x5 - m) + __expf(x6 - m) + __expf(x7 - m);
    float lse = __logf(s) + m;
    float xt;
    switch (t) {
        case 0: xt = x0; break; case 1: xt = x1; break;
        case 2: xt = x2; break; case 3: xt = x3; break;
        case 4: xt = x4; break; case 5: xt = x5; break;
        case 6: xt = x6; break; default: xt = x7; break;
    }
    float ce = lse - xt;              // >= 0
    float pt = __expf(-ce);           // (0, 1]
    float om = 1.0f - pt;
    return om * om * ce;              // >= 0
}

// per-thread batch: 2 consecutive nodes (R11 structure + prefetch regs)
struct Batch {
    float4 a0, a1, b0, b1;
    int ta, tb, ca, cb;
    bool v;
};

__device__ __forceinline__ Batch load_batch(const float4* __restrict__ lgf,
                                            const int* __restrict__ targets,
                                            const int* __restrict__ cid,
                                            int i0, int cend) {
    Batch b;
    b.v = (i0 < cend);
    if (b.v) {
        const float4* p = lgf + (size_t)i0 * 2;
        b.a0 = p[0]; b.a1 = p[1]; b.b0 = p[2]; b.b1 = p[3];  // chunk is even: i0<cend => i0+1<cend
        int2 tt = *reinterpret_cast<const int2*>(targets + i0);
        int2 cc = *reinterpret_cast<const int2*>(cid + i0);
        b.ta = tt.x; b.tb = tt.y; b.ca = cc.x; b.cb = cc.y;
    } else {
        b.a0 = b.a1 = b.b0 = b.b1 = make_float4(0.f, 0.f, 0.f, 0.f);
        b.ta = b.tb = 0; b.ca = -1; b.cb = -2;   // mismatching sentinels
    }
    return b;
}

// ---------------------------------------------------------------------------
// Kernel 1 (fused): R11 structure (2 nodes/thread) + REGISTER DOUBLE-BUFFER
// PREFETCH (R12 lesson: unit-stride was neutral -> latency-bound; VGPR=20
// meant zero look-ahead). Next iteration's 6 loads are issued before the
// current iteration's transcendental chain.
// ---------------------------------------------------------------------------
__global__ __launch_bounds__(BLOCK) void node_loss_kernel(
        const float* __restrict__ logits,   // [N, 8]
        const int* __restrict__ targets,    // [N]
        const int* __restrict__ cid,        // [N], sorted
        float* __restrict__ seg_sum,        // [K]
        unsigned* __restrict__ seg_maxb,    // [K]
        unsigned* __restrict__ seg_cnt,     // [K]
        unsigned* __restrict__ shard_tk,    // [NSHARDS*16]
        unsigned* __restrict__ stage2_tk,   // [16]
        float* __restrict__ out,
        int n) {
    __shared__ float lsum[WIN];
    __shared__ int   lmax[WIN];
    __shared__ unsigned s_last;
    __shared__ float s_fa[4], s_fn[4];

    const int tid  = threadIdx.x;
    const int lane = tid & 63;

    const int chunk  = (n + NBLOCKS - 1) / NBLOCKS;   // 1954 for N=4M (even)
    const int cstart = blockIdx.x * chunk;

    if (cstart < n) {
        const int cend = min(cstart + chunk, n);
        const int base = cid[cstart];                 // broadcast load

        for (int j = tid; j < WIN; j += BLOCK) {
            lsum[j] = 0.0f;
            lmax[j] = (int)NEG_INF_BITS;
        }
        __syncthreads();

        const float4* lgf = reinterpret_cast<const float4*>(logits);

        int i0 = cstart + tid * 2;
        Batch cur = load_batch(lgf, targets, cid, i0, cend);

        while (__any(i0 < cend)) {
            // ---- prefetch next iteration BEFORE current compute ----
            const int i0n = i0 + BLOCK * 2;
            const bool any_next = __any(i0n < cend);
            Batch nxt;
            if (any_next) nxt = load_batch(lgf, targets, cid, i0n, cend);

            // ---- compute current from registers ----
            float la = 0.0f, lb = 0.0f;
            int offa = -1, offb = -2;
            if (cur.v) {
                la = node_focal(cur.a0, cur.a1, cur.ta);
                lb = node_focal(cur.b0, cur.b1, cur.tb);
                offa = cur.ca - base;
                offb = cur.cb - base;
            }

            int u = __shfl(offa, 0);
            bool uniform = __all(offa == u && offb == u) && (u < WIN);
            if (uniform) {
                // all 128 nodes one segment: pair-combine then one butterfly
                float tsum = la + lb;
                float tmax = fmaxf(la, lb);
                #pragma unroll
                for (int o = 32; o > 0; o >>= 1) {
                    tsum += __shfl_xor(tsum, o);
                    tmax = fmaxf(tmax, __shfl_xor(tmax, o));
                }
                if (lane == 0) {
                    atomicAdd(&lsum[u], tsum);
                    atomicMax(&lmax[u], __float_as_int(tmax));
                }
            } else {
                if (cur.v) {
                    if (offa < WIN) {
                        atomicAdd(&lsum[offa], la);
                        atomicMax(&lmax[offa], __float_as_int(la));
                    } else {  // pathological overflow: direct global accumulate
                        atomicAdd(&seg_sum[base + offa], la);
                        atomicMax(&seg_maxb[base + offa], __float_as_uint(la));
                        atomicAdd(&seg_cnt[base + offa], 1u);
                    }
                    if (offb < WIN) {
                        atomicAdd(&lsum[offb], lb);
                        atomicMax(&lmax[offb], __float_as_int(lb));
                    } else {
                        atomicAdd(&seg_sum[base + offb], lb);
                        atomicMax(&seg_maxb[base + offb], __float_as_uint(lb));
                        atomicAdd(&seg_cnt[base + offb], 1u);
                    }
                }
            }

            i0 = i0n;
            cur = nxt;          // dead when !any_next (loop exits)
        }
        __syncthreads();

        // flush touched window entries: ~5-10 global atomic triples per block
        for (int j = tid; j < WIN; j += BLOCK) {
            int mb = lmax[j];
            if (mb != (int)NEG_INF_BITS) {
                atomicAdd(&seg_sum[base + j], lsum[j]);
                atomicMax(&seg_maxb[base + j], (unsigned)mb);  // mb >= 0 bits
                atomicAdd(&seg_cnt[base + j], 1u);
            }
        }
    }

    // ---- sharded ticket: last finished block overall runs the finalize ----
    asm volatile("s_waitcnt vmcnt(0)" ::: "memory");  // own flush atomics acked
    __syncthreads();                                  // whole block drained
    if (tid == 0) {
        unsigned fin = 0u;
        unsigned my = atomicAdd(&shard_tk[(blockIdx.x / SHARD_SZ) * 16], 1u);
        if (my == (unsigned)(SHARD_SZ - 1)) {
            fin = atomicAdd(&stage2_tk[0], 1u) + 1u;
        }
        s_last = (fin == (unsigned)NSHARDS) ? 1u : 0u;
    }
    __syncthreads();
    if (s_last) {
        float acc = 0.0f, np = 0.0f;
        // Pipelined: unconditional agent-scope loads, unrolled -> many in flight
        #pragma unroll 8
        for (int k = tid; k < K_SEGS; k += BLOCK) {
            unsigned c = __hip_atomic_load(&seg_cnt[k],  __ATOMIC_RELAXED, __HIP_MEMORY_SCOPE_AGENT);
            float s    = __hip_atomic_load(&seg_sum[k],  __ATOMIC_RELAXED, __HIP_MEMORY_SCOPE_AGENT);
            unsigned m = __hip_atomic_load(&seg_maxb[k], __ATOMIC_RELAXED, __HIP_MEMORY_SCOPE_AGENT);
            if (c != 0u) {
                acc += ALPHA_W * s + (1.0f - ALPHA_W) * __uint_as_float(m);
                np += 1.0f;
            }
        }
        #pragma unroll
        for (int o = 32; o > 0; o >>= 1) {
            acc += __shfl_xor(acc, o);
            np  += __shfl_xor(np, o);
        }
        if (lane == 0) { s_fa[tid >> 6] = acc; s_fn[tid >> 6] = np; }
        __syncthreads();
        if (tid == 0) {
            float a = s_fa[0] + s_fa[1] + s_fa[2] + s_fa[3];
            float c = s_fn[0] + s_fn[1] + s_fn[2] + s_fn[3];
            out[0] = a / fmaxf(c, 1.0f);
        }
    }
}

// ---------------------------------------------------------------------------
extern "C" void kernel_launch(void* const* d_in, const int* in_sizes, int n_in,
                              void* d_out, int out_size, void* d_ws, size_t ws_size,
                              hipStream_t stream) {
    const float* logits = (const float*)d_in[0];
    const int* targets  = (const int*)d_in[1];
    const int* cid      = (const int*)d_in[2];
    float* out          = (float*)d_out;

    const int n = in_sizes[1];   // N = 4,000,000

    unsigned* w        = (unsigned*)d_ws;
    float* seg_sum     = (float*)w;
    unsigned* seg_maxb = w + K_SEGS;
    unsigned* seg_cnt  = w + 2 * K_SEGS;
    unsigned* shard_tk = w + SHARD_BASE;
    unsigned* stage2_tk= w + STAGE2_OFF;

    init_ws_kernel<<<(WS_WORDS + 255) / 256, 256, 0, stream>>>(w);

    node_loss_kernel<<<NBLOCKS, BLOCK, 0, stream>>>(logits, targets, cid,
                                                    seg_sum, seg_maxb, seg_cnt,
                                                    shard_tk, stage2_tk, out, n);
}